// Round 3
// baseline (7543.539 us; speedup 1.0000x reference)
//
#include <hip/hip_runtime.h>

#define N 4096
#define IN_DIM 128
#define T_STEPS 2048
#define KSLOTS 576           // uniform padded ELL row width; max nnz ~490 (mean 409.6, sd 19.2)
#define CHUNKS (KSLOTS / 64) // 9, uniform for all rows
#define NBLOCKS 64
#define NTHREADS 1024
#define ROWS_PER_WAVE 4
#define ROWS_PER_BLOCK (ROWS_PER_WAVE * (NTHREADS / 64))   // 64
#define SENTINEL_BITS 0x7FC00001u   // qNaN; h is always finite -> producers never write this

typedef float f32x4 __attribute__((ext_vector_type(4)));

// ---------------------------------------------------------------------------
// Kernel 0: fill out with the sentinel, write-through (agent scope) so it is
// at the coherence point before any step-kernel poll. Defends against 0xAA
// poison and stale floats from a previous replay (both non-sentinel).
// ---------------------------------------------------------------------------
__global__ void init_sentinel(float* __restrict__ out) {
    const size_t i = (size_t)blockIdx.x * blockDim.x + threadIdx.x;
    __hip_atomic_store(&out[i], __uint_as_float(SENTINEL_BITS),
                       __ATOMIC_RELAXED, __HIP_MEMORY_SCOPE_AGENT);
}

// ---------------------------------------------------------------------------
// Kernel 1: dense W -> uniform padded ELL with bank-aware chunk assignment
// (each 64-slot chunk hits every LDS bank ~2x; 2-way is free on gfx950).
// Padding: val=0, col=0 (same-address broadcast, free). Unchanged since R2.
// ---------------------------------------------------------------------------
__global__ void build_ell(const float* __restrict__ W,
                          float* __restrict__ vals,
                          unsigned short* __restrict__ cols) {
    __shared__ float sval[KSLOTS];
    __shared__ unsigned short scol[KSLOTS];
    __shared__ float slot_val[KSLOTS];
    __shared__ unsigned short slot_col[KSLOTS];
    __shared__ int chunk_fill[CHUNKS];
    __shared__ int cnt;

    const int r = blockIdx.x;
    const int tid = threadIdx.x;
    if (tid == 0) cnt = 0;
    if (tid < CHUNKS) chunk_fill[tid] = 0;
    __syncthreads();

    const float* wrow = W + (size_t)r * N;
    for (int j = tid; j < N; j += blockDim.x) {
        float w = wrow[j];
        if (w != 0.0f) {
            int p = atomicAdd(&cnt, 1);
            if (p < KSLOTS) { sval[p] = w; scol[p] = (unsigned short)j; }
        }
    }
    __syncthreads();
    for (int j = tid; j < KSLOTS; j += blockDim.x) { slot_val[j] = 0.0f; slot_col[j] = 0; }
    __syncthreads();

    if (tid < 32) {  // one thread per bank spreads its entries across chunks
        int k = 0;
        const int n = (cnt < KSLOTS) ? cnt : KSLOTS;
        for (int p = 0; p < n; ++p) {
            int c = scol[p];
            if ((c & 31) == tid) {
                int ch0 = (k + tid) % CHUNKS;
                for (int probe = 0; probe < CHUNKS; ++probe) {
                    int cc = ch0 + probe; if (cc >= CHUNKS) cc -= CHUNKS;
                    int pos = atomicAdd(&chunk_fill[cc], 1);
                    if (pos < 64) {
                        slot_val[cc * 64 + pos] = sval[p];
                        slot_col[cc * 64 + pos] = (unsigned short)c;
                        break;
                    }
                }
                ++k;
            }
        }
    }
    __syncthreads();

    float* vrow = vals + (size_t)r * KSLOTS;
    unsigned short* crow = cols + (size_t)r * KSLOTS;
    for (int j = tid; j < KSLOTS; j += blockDim.x) { vrow[j] = slot_val[j]; crow[j] = slot_col[j]; }
}

// ---------------------------------------------------------------------------
// Coherent 16B accesses straight at the coherence point (bypass L1+L2).
// Load form is R4/R9-proven (passed full harness incl. replay tripwires).
// ---------------------------------------------------------------------------
__device__ __forceinline__ f32x4 load_coherent_x4(const float* p) {
    f32x4 v;
    asm volatile("global_load_dwordx4 %0, %1, off sc0 sc1\n\t"
                 "s_waitcnt vmcnt(0)"
                 : "=v"(v) : "v"(p) : "memory");
    return v;
}

__device__ __forceinline__ void store_coherent_x4(float* p, f32x4 v) {
    asm volatile("global_store_dwordx4 %0, %1, off sc0 sc1"
                 :: "v"(p), "v"(v) : "memory");
}

// Branch-free tanh (validated R6-first-launch + R9: absmax 3.9e-3 unchanged).
__device__ __forceinline__ float fast_tanh(float v) {
    float ax = __builtin_fabsf(v);
    float e  = __builtin_amdgcn_exp2f(ax * 2.88539008177793f);  // 2*log2(e)
    float r  = 1.0f - 2.0f * __builtin_amdgcn_rcpf(e + 1.0f);
    return __builtin_copysignf(r, v);
}

// ---------------------------------------------------------------------------
// Kernel 2: persistent step kernel — R9/R11 proven skeleton (single h buffer,
// s_sleep(1) sentinel poll, data-as-flag, coherent 16B accesses).
// R12 change: ROWS_PER_WAVE 2->4, NBLOCKS 128->64. Each wave's 4 rows now
// form exactly ONE 16B output granule, stored by that wave itself right
// after its own reduce:
//   - barrier 2 + hout collect + wave-0 relay are REMOVED from the store
//     path (barrier 2 now only orders h_lds reuse, after the store issue);
//   - total coherent poll/staging traffic per round halves (64 x 16KB);
//   - R11's single-store-per-granule invariant is preserved exactly.
// Cost: 36 gathers/lane (vs 18) and ~2x VGPRs (~100, still fine at 16 waves).
// ---------------------------------------------------------------------------
__global__ void __launch_bounds__(NTHREADS, 1) esn_steps(
    const float* __restrict__ x,
    const float* __restrict__ W_in,
    const float* __restrict__ vals,
    const unsigned short* __restrict__ cols,
    float* __restrict__ out) {

    __shared__ float h_lds[N];       // full previous state, 16 KB
    __shared__ float x_lds[IN_DIM];

    const int tid  = threadIdx.x;
    const int lane = tid & 63;
    const int wave = tid >> 6;
    const int base = blockIdx.x * ROWS_PER_BLOCK + wave * ROWS_PER_WAVE;  // 4 rows/wave

    // Per-row W_in slices.
    float w0[ROWS_PER_WAVE], w1[ROWS_PER_WAVE];
    #pragma unroll
    for (int j = 0; j < ROWS_PER_WAVE; ++j) {
        w0[j] = W_in[(base + j) * IN_DIM + lane];
        w1[j] = W_in[(base + j) * IN_DIM + 64 + lane];
    }

    // Hoist the 4-row ELL slice into registers (36 vals + 36 byte offsets).
    float rv[ROWS_PER_WAVE][CHUNKS];
    int   rc[ROWS_PER_WAVE][CHUNKS];
    #pragma unroll
    for (int j = 0; j < ROWS_PER_WAVE; ++j) {
        const float* vp = vals + (size_t)(base + j) * KSLOTS;
        const unsigned short* cp = cols + (size_t)(base + j) * KSLOTS;
        #pragma unroll
        for (int i = 0; i < CHUNKS; ++i) {
            rv[j][i] = vp[(i << 6) + lane];
            rc[j][i] = ((int)cp[(i << 6) + lane]) << 2;
        }
    }

    const int i4 = tid << 2;

    for (int t = 0; t < T_STEPS; ++t) {
        // ---- stage x_t on the LAST two waves (overlaps the poll) ----
        if (tid >= NTHREADS - IN_DIM) {
            const int xi = tid - (NTHREADS - IN_DIM);
            x_lds[xi] = x[t * IN_DIM + xi];
        }

        // ---- stage h_{t-1}: coherent dwordx4 poll until sentinel gone ----
        // Each 16B granule is written by exactly one 16B store (R11 invariant).
        f32x4 hv;
        if (t > 0) {
            const float* addr = out + (size_t)(t - 1) * N + i4;
            for (;;) {
                hv = load_coherent_x4(addr);
                bool not_ready = (__float_as_uint(hv.x) == SENTINEL_BITS) |
                                 (__float_as_uint(hv.y) == SENTINEL_BITS) |
                                 (__float_as_uint(hv.z) == SENTINEL_BITS) |
                                 (__float_as_uint(hv.w) == SENTINEL_BITS);
                if (!not_ready) break;
                __builtin_amdgcn_s_sleep(1);
            }
        } else {
            hv = (f32x4)(0.0f);
        }
        ((f32x4*)h_lds)[tid] = hv;
        __syncthreads();   // barrier 1: h_lds (and x_lds) fully staged

        // ---- 4 row dots: input part + register-ELL sparse gather ----
        float acc[ROWS_PER_WAVE];
        const float xa = x_lds[lane], xb = x_lds[64 + lane];
        #pragma unroll
        for (int j = 0; j < ROWS_PER_WAVE; ++j) acc[j] = w0[j] * xa + w1[j] * xb;

        #pragma unroll
        for (int j = 0; j < ROWS_PER_WAVE; ++j) {
            #pragma unroll
            for (int i = 0; i < CHUNKS; ++i) {
                acc[j] += rv[j][i] * *(const float*)((const char*)h_lds + rc[j][i]);
            }
        }

        // butterfly reduce each acc[j] across the wave
        #pragma unroll
        for (int j = 0; j < ROWS_PER_WAVE; ++j) {
            #pragma unroll
            for (int off = 32; off > 0; off >>= 1)
                acc[j] += __shfl_xor(acc[j], off);
        }

        // ---- finalize: lanes 0..3 each produce one row, shfl-pack into
        //      lane 0, ONE coherent 16B store per wave, issued immediately ----
        {
            const int r3 = lane & 3;
            float a = (r3 == 0) ? acc[0] : (r3 == 1) ? acc[1]
                    : (r3 == 2) ? acc[2] : acc[3];
            float hp = h_lds[base + r3];
            float hn = 0.7f * hp + 0.3f * fast_tanh(a);
            f32x4 v;
            v.x = __shfl(hn, 0); v.y = __shfl(hn, 1);
            v.z = __shfl(hn, 2); v.w = __shfl(hn, 3);
            if (lane == 0)
                store_coherent_x4(out + (size_t)t * N + base, v);
        }

        __syncthreads();   // barrier 2: all h_lds reads done before next stage
    }
}

// ---------------------------------------------------------------------------
// Workspace layout (bytes):
//   [0, +N*KSLOTS*4)       ELL vals (f32)   9.44 MB
//   [.., +N*KSLOTS*2)      ELL cols (u16)   4.72 MB
// ---------------------------------------------------------------------------
extern "C" void kernel_launch(void* const* d_in, const int* in_sizes, int n_in,
                              void* d_out, int out_size, void* d_ws, size_t ws_size,
                              hipStream_t stream) {
    const float* x    = (const float*)d_in[0];  // [2048,128]
    const float* W_in = (const float*)d_in[1];  // [4096,128]
    const float* W    = (const float*)d_in[2];  // [4096,4096]
    float* out = (float*)d_out;                 // [2048,4096]

    char* ws = (char*)d_ws;
    float* vals = (float*)ws;
    unsigned short* cols = (unsigned short*)(ws + (size_t)N * KSLOTS * 4);

    init_sentinel<<<(T_STEPS * N) / NTHREADS, NTHREADS, 0, stream>>>(out);
    build_ell<<<N, 256, 0, stream>>>(W, vals, cols);

    void* args[] = {(void*)&x, (void*)&W_in, (void*)&vals, (void*)&cols, (void*)&out};
    hipLaunchCooperativeKernel((void*)esn_steps, dim3(NBLOCKS), dim3(NTHREADS),
                               args, 0, stream);
}

// Round 4
// 4598.774 us; speedup vs baseline: 1.6403x; 1.6403x over previous
//
#include <hip/hip_runtime.h>

#define N 4096
#define IN_DIM 128
#define T_STEPS 2048
#define KSLOTS 576           // uniform padded ELL row width; max nnz ~490 (mean 409.6, sd 19.2)
#define CHUNKS (KSLOTS / 64) // 9, uniform for all rows
#define NBLOCKS 128
#define NTHREADS 1024
#define ROWS_PER_WAVE 2
#define ROWS_PER_BLOCK (ROWS_PER_WAVE * (NTHREADS / 64))   // 32
#define SENTINEL_BITS 0x7FC00001u   // qNaN; h is always finite -> producers never write this

typedef float f32x4 __attribute__((ext_vector_type(4)));

// ---------------------------------------------------------------------------
// Kernel 0: fill out with the sentinel, write-through (agent scope) so it is
// at the coherence point before any step-kernel poll. Defends against 0xAA
// poison and stale floats from a previous replay (both non-sentinel).
// ---------------------------------------------------------------------------
__global__ void init_sentinel(float* __restrict__ out) {
    const size_t i = (size_t)blockIdx.x * blockDim.x + threadIdx.x;
    __hip_atomic_store(&out[i], __uint_as_float(SENTINEL_BITS),
                       __ATOMIC_RELAXED, __HIP_MEMORY_SCOPE_AGENT);
}

// ---------------------------------------------------------------------------
// Kernel 1: dense W -> uniform padded ELL with bank-aware chunk assignment
// (each 64-slot chunk hits every LDS bank ~2x; 2-way is free on gfx950).
// Padding: val=0, col=0 (same-address broadcast, free). Unchanged since R2.
// ---------------------------------------------------------------------------
__global__ void build_ell(const float* __restrict__ W,
                          float* __restrict__ vals,
                          unsigned short* __restrict__ cols) {
    __shared__ float sval[KSLOTS];
    __shared__ unsigned short scol[KSLOTS];
    __shared__ float slot_val[KSLOTS];
    __shared__ unsigned short slot_col[KSLOTS];
    __shared__ int chunk_fill[CHUNKS];
    __shared__ int cnt;

    const int r = blockIdx.x;
    const int tid = threadIdx.x;
    if (tid == 0) cnt = 0;
    if (tid < CHUNKS) chunk_fill[tid] = 0;
    __syncthreads();

    const float* wrow = W + (size_t)r * N;
    for (int j = tid; j < N; j += blockDim.x) {
        float w = wrow[j];
        if (w != 0.0f) {
            int p = atomicAdd(&cnt, 1);
            if (p < KSLOTS) { sval[p] = w; scol[p] = (unsigned short)j; }
        }
    }
    __syncthreads();
    for (int j = tid; j < KSLOTS; j += blockDim.x) { slot_val[j] = 0.0f; slot_col[j] = 0; }
    __syncthreads();

    if (tid < 32) {  // one thread per bank spreads its entries across chunks
        int k = 0;
        const int n = (cnt < KSLOTS) ? cnt : KSLOTS;
        for (int p = 0; p < n; ++p) {
            int c = scol[p];
            if ((c & 31) == tid) {
                int ch0 = (k + tid) % CHUNKS;
                for (int probe = 0; probe < CHUNKS; ++probe) {
                    int cc = ch0 + probe; if (cc >= CHUNKS) cc -= CHUNKS;
                    int pos = atomicAdd(&chunk_fill[cc], 1);
                    if (pos < 64) {
                        slot_val[cc * 64 + pos] = sval[p];
                        slot_col[cc * 64 + pos] = (unsigned short)c;
                        break;
                    }
                }
                ++k;
            }
        }
    }
    __syncthreads();

    float* vrow = vals + (size_t)r * KSLOTS;
    unsigned short* crow = cols + (size_t)r * KSLOTS;
    for (int j = tid; j < KSLOTS; j += blockDim.x) { vrow[j] = slot_val[j]; crow[j] = slot_col[j]; }
}

// ---------------------------------------------------------------------------
// Coherent 16B accesses straight at the coherence point (bypass L1+L2).
// Load form is R4/R9-proven (passed full harness incl. replay tripwires).
// ---------------------------------------------------------------------------
__device__ __forceinline__ f32x4 load_coherent_x4(const float* p) {
    f32x4 v;
    asm volatile("global_load_dwordx4 %0, %1, off sc0 sc1\n\t"
                 "s_waitcnt vmcnt(0)"
                 : "=v"(v) : "v"(p) : "memory");
    return v;
}

__device__ __forceinline__ void store_coherent_x4(float* p, f32x4 v) {
    asm volatile("global_store_dwordx4 %0, %1, off sc0 sc1"
                 :: "v"(p), "v"(v) : "memory");
}

__device__ __forceinline__ bool granule_not_ready(f32x4 hv) {
    return (__float_as_uint(hv.x) == SENTINEL_BITS) |
           (__float_as_uint(hv.y) == SENTINEL_BITS) |
           (__float_as_uint(hv.z) == SENTINEL_BITS) |
           (__float_as_uint(hv.w) == SENTINEL_BITS);
}

// Branch-free tanh (validated R6-first-launch + R9: absmax 3.9e-3 unchanged).
__device__ __forceinline__ float fast_tanh(float v) {
    float ax = __builtin_fabsf(v);
    float e  = __builtin_amdgcn_exp2f(ax * 2.88539008177793f);  // 2*log2(e)
    float r  = 1.0f - 2.0f * __builtin_amdgcn_rcpf(e + 1.0f);
    return __builtin_copysignf(r, v);
}

// ---------------------------------------------------------------------------
// Kernel 2: persistent step kernel — EXACT R11 skeleton (proven 5089 us):
// 128 blocks, 2 rows/wave, LDS hout collect, single coalesced 128B wave-0
// store per block (full-line, single-producer-per-granule invariant).
// R13 single-variable change: poll PACING. The old loop (load, s_sleep(1))
// re-reads 2MB/round chip-wide as fast as RT allows; the first 1-2 rounds
// are guaranteed misses (producers need >=~1100cy of compute after barrier 2
// before their store can reach the MALL, polls start ~100cy after). New
// pacing: initial s_sleep(8) (512cy, below earliest-arrival ~700cy => free),
// then ladder s_sleep(1), s_sleep(2), steady s_sleep(4) (256cy cap =>
// bounded alignment penalty). ~35-45% fewer coherent poll transactions/step.
// Tests the fabric-saturation theory with zero change to any proven
// store/visibility/sentinel semantics.
// ---------------------------------------------------------------------------
__global__ void __launch_bounds__(NTHREADS, 1) esn_steps(
    const float* __restrict__ x,
    const float* __restrict__ W_in,
    const float* __restrict__ vals,
    const unsigned short* __restrict__ cols,
    float* __restrict__ out) {

    __shared__ float h_lds[N];       // full previous state, 16 KB
    __shared__ float x_lds[IN_DIM];
    __shared__ __align__(16) float hout[ROWS_PER_BLOCK];  // block's 32 new rows

    const int tid  = threadIdx.x;
    const int lane = tid & 63;
    const int wave = tid >> 6;
    const int blockBase = blockIdx.x * ROWS_PER_BLOCK;
    const int base = blockBase + wave * ROWS_PER_WAVE;  // 2 rows/wave

    // Per-row W_in slices.
    float w0[ROWS_PER_WAVE], w1[ROWS_PER_WAVE];
    #pragma unroll
    for (int j = 0; j < ROWS_PER_WAVE; ++j) {
        w0[j] = W_in[(base + j) * IN_DIM + lane];
        w1[j] = W_in[(base + j) * IN_DIM + 64 + lane];
    }

    // Hoist the 2-row ELL slice into registers (18 vals + 18 byte offsets).
    float rv[ROWS_PER_WAVE][CHUNKS];
    int   rc[ROWS_PER_WAVE][CHUNKS];
    #pragma unroll
    for (int j = 0; j < ROWS_PER_WAVE; ++j) {
        const float* vp = vals + (size_t)(base + j) * KSLOTS;
        const unsigned short* cp = cols + (size_t)(base + j) * KSLOTS;
        #pragma unroll
        for (int i = 0; i < CHUNKS; ++i) {
            rv[j][i] = vp[(i << 6) + lane];
            rc[j][i] = ((int)cp[(i << 6) + lane]) << 2;
        }
    }

    const int i4 = tid << 2;

    for (int t = 0; t < T_STEPS; ++t) {
        // ---- stage x_t on the LAST two waves (overlaps the poll) ----
        if (tid >= NTHREADS - IN_DIM) {
            const int xi = tid - (NTHREADS - IN_DIM);
            x_lds[xi] = x[t * IN_DIM + xi];
        }

        // ---- stage h_{t-1}: paced coherent dwordx4 poll (R13 ladder) ----
        f32x4 hv;
        if (t > 0) {
            const float* addr = out + (size_t)(t - 1) * N + i4;
            __builtin_amdgcn_s_sleep(8);           // skip guaranteed-miss round
            hv = load_coherent_x4(addr);
            if (granule_not_ready(hv)) {
                __builtin_amdgcn_s_sleep(1);
                hv = load_coherent_x4(addr);
                if (granule_not_ready(hv)) {
                    __builtin_amdgcn_s_sleep(2);
                    hv = load_coherent_x4(addr);
                    while (granule_not_ready(hv)) {
                        __builtin_amdgcn_s_sleep(4);   // steady 256cy cap
                        hv = load_coherent_x4(addr);
                    }
                }
            }
        } else {
            hv = (f32x4)(0.0f);
        }
        ((f32x4*)h_lds)[tid] = hv;
        __syncthreads();   // barrier 1: h_lds (and x_lds) fully staged

        // ---- 2 row dots: input part + register-ELL sparse gather ----
        float acc[ROWS_PER_WAVE];
        const float xa = x_lds[lane], xb = x_lds[64 + lane];
        #pragma unroll
        for (int j = 0; j < ROWS_PER_WAVE; ++j) acc[j] = w0[j] * xa + w1[j] * xb;

        #pragma unroll
        for (int j = 0; j < ROWS_PER_WAVE; ++j) {
            #pragma unroll
            for (int i = 0; i < CHUNKS; ++i) {
                acc[j] += rv[j][i] * *(const float*)((const char*)h_lds + rc[j][i]);
            }
        }

        // butterfly reduce each acc[j] across the wave
        #pragma unroll
        for (int j = 0; j < ROWS_PER_WAVE; ++j) {
            #pragma unroll
            for (int off = 32; off > 0; off >>= 1)
                acc[j] += __shfl_xor(acc[j], off);
        }

        // lanes 0..1 finalize into the LDS collect buffer (one row each)
        if (lane < ROWS_PER_WAVE) {
            float a = (lane == 0) ? acc[0] : acc[1];
            float hp = h_lds[base + lane];
            float hn = 0.7f * hp + 0.3f * fast_tanh(a);
            hout[wave * ROWS_PER_WAVE + lane] = hn;
        }
        __syncthreads();   // barrier 2: collect done + all h_lds reads done

        // ---- wave 0 emits the block's 32 rows as one coalesced 128B store;
        //      the other 15 waves proceed straight to the next step's poll ----
        if (tid < ROWS_PER_BLOCK / 4) {
            f32x4 hv4 = ((const f32x4*)hout)[tid];
            store_coherent_x4(out + (size_t)t * N + blockBase + (tid << 2), hv4);
        }
    }
}

// ---------------------------------------------------------------------------
// Workspace layout (bytes):
//   [0, +N*KSLOTS*4)       ELL vals (f32)   9.44 MB
//   [.., +N*KSLOTS*2)      ELL cols (u16)   4.72 MB
// ---------------------------------------------------------------------------
extern "C" void kernel_launch(void* const* d_in, const int* in_sizes, int n_in,
                              void* d_out, int out_size, void* d_ws, size_t ws_size,
                              hipStream_t stream) {
    const float* x    = (const float*)d_in[0];  // [2048,128]
    const float* W_in = (const float*)d_in[1];  // [4096,128]
    const float* W    = (const float*)d_in[2];  // [4096,4096]
    float* out = (float*)d_out;                 // [2048,4096]

    char* ws = (char*)d_ws;
    float* vals = (float*)ws;
    unsigned short* cols = (unsigned short*)(ws + (size_t)N * KSLOTS * 4);

    init_sentinel<<<(T_STEPS * N) / NTHREADS, NTHREADS, 0, stream>>>(out);
    build_ell<<<N, 256, 0, stream>>>(W, vals, cols);

    void* args[] = {(void*)&x, (void*)&W_in, (void*)&vals, (void*)&cols, (void*)&out};
    hipLaunchCooperativeKernel((void*)esn_steps, dim3(NBLOCKS), dim3(NTHREADS),
                               args, 0, stream);
}